// Round 14
// baseline (349.439 us; speedup 1.0000x reference)
//
#include <hip/hip_runtime.h>

#define S_LEN 2048
#define BATCH 4
#define DMODEL 1024
#define NHEAD 16
#define MROWS (S_LEN * BATCH)   // 8192
#define MOD6 (6 * DMODEL)       // 6144

typedef float f32x4 __attribute__((ext_vector_type(4)));
typedef short bf16x8 __attribute__((ext_vector_type(8)));
typedef unsigned short ushort_t;

__device__ __forceinline__ unsigned short f2bf(float f) {
  unsigned u = __float_as_uint(f);
  u += 0x7FFF + ((u >> 16) & 1);   // round-to-nearest-even
  return (unsigned short)(u >> 16);
}
__device__ __forceinline__ float bf2f(unsigned short h) {
  return __uint_as_float(((unsigned)h) << 16);
}
__device__ __forceinline__ float wave_sum(float v) {
#pragma unroll
  for (int off = 32; off > 0; off >>= 1) v += __shfl_xor(v, off, 64);
  return v;
}
__device__ __forceinline__ void mfma16(f32x4& c, bf16x8 a, bf16x8 b) {
  asm volatile("v_mfma_f32_16x16x32_bf16 %0, %1, %2, %0" : "+v"(c) : "v"(a), "v"(b));
}
// Fence between MFMA writes and VALU reads of acc: sched_barrier pins all code
// motion; 24 wait-states cover the MFMA->VALU RAW hazard window.
__device__ __forceinline__ void mfma_fence() {
  __builtin_amdgcn_sched_barrier(0);
  asm volatile("s_nop 7\n\ts_nop 7\n\ts_nop 7");
  __builtin_amdgcn_sched_barrier(0);
}
__device__ __forceinline__ void async16(const void* g, void* l) {
  __builtin_amdgcn_global_load_lds((const __attribute__((address_space(1))) void*)g,
                                   (__attribute__((address_space(3))) void*)l, 16, 0, 0);
}

// ---------------- fused weight cast fp32 -> bf16 (all four weights, one launch) ----
#define N4_INW  786432          // 3072*1024/4
#define N4_OUTW 262144          // 1024*1024/4
#define N4_W1   1048576         // 4096*1024/4
#define N4_W2   1048576         // 1024*4096/4
#define N4_ALL  (N4_INW + N4_OUTW + N4_W1 + N4_W2)
__launch_bounds__(256)
__global__ void castk_all(const float4* __restrict__ inw, const float4* __restrict__ outw,
                          const float4* __restrict__ w1, const float4* __restrict__ w2,
                          ushort4* __restrict__ dq, ushort4* __restrict__ dow,
                          ushort4* __restrict__ dw1, ushort4* __restrict__ dw2) {
  int i = blockIdx.x * 256 + threadIdx.x;
  if (i >= N4_ALL) return;
  const float4* src;
  ushort4* dst;
  int j = i;
  if (j < N4_INW) { src = inw; dst = dq; }
  else if ((j -= N4_INW) < N4_OUTW) { src = outw; dst = dow; }
  else if ((j -= N4_OUTW) < N4_W1) { src = w1; dst = dw1; }
  else { j -= N4_W1; src = w2; dst = dw2; }
  float4 v = src[j];
  ushort4 o;
  o.x = f2bf(v.x); o.y = f2bf(v.y); o.z = f2bf(v.z); o.w = f2bf(v.w);
  dst[j] = o;
}

// ---------------- mod = relu(c) @ ada_w.T + ada_b : [B, 6D] fp32 ----------------
__launch_bounds__(256)
__global__ void ada_k(const float* __restrict__ c, const float* __restrict__ aw,
                      const float* __restrict__ ab, float* __restrict__ mod) {
  int j = blockIdx.x;           // 0..6143
  int b = threadIdx.x >> 6;     // wave -> batch
  int l = threadIdx.x & 63;
  const float* wrow = aw + (size_t)j * DMODEL;
  const float* crow = c + b * DMODEL;
  float s = 0.f;
#pragma unroll 4
  for (int i = l; i < DMODEL; i += 64) {
    float cv = crow[i];
    cv = cv > 0.f ? cv : 0.f;
    s += cv * wrow[i];
  }
  s = wave_sum(s);
  if (l == 0) mod[b * MOD6 + j] = s + ab[j];
}

// ---------------- LN + AdaLN modulate -> bf16 ----------------
__launch_bounds__(256)
__global__ void ln_mod(const float* __restrict__ x, const float* __restrict__ mod,
                       int sh_off, int sc_off, ushort_t* __restrict__ out) {
  __shared__ float red[8];
  int row = blockIdx.x;         // s*B + b
  int b = row & 3;
  int tid = threadIdx.x;
  const float4* xr = (const float4*)(x + (size_t)row * DMODEL);
  float4 v = xr[tid];
  float s = v.x + v.y + v.z + v.w;
  float s2 = v.x * v.x + v.y * v.y + v.z * v.z + v.w * v.w;
  s = wave_sum(s);
  s2 = wave_sum(s2);
  int w = tid >> 6, l = tid & 63;
  if (l == 0) { red[w] = s; red[4 + w] = s2; }
  __syncthreads();
  s = red[0] + red[1] + red[2] + red[3];
  s2 = red[4] + red[5] + red[6] + red[7];
  float mean = s * (1.0f / DMODEL);
  float var = s2 * (1.0f / DMODEL) - mean * mean;
  float inv = rsqrtf(var + 1e-6f);
  const float* shp = mod + b * MOD6 + sh_off;
  const float* scp = mod + b * MOD6 + sc_off;
  float vv[4] = {v.x, v.y, v.z, v.w};
  ushort4 ov;
  ushort_t* op = (ushort_t*)&ov;
#pragma unroll
  for (int j = 0; j < 4; j++) {
    int idx = tid * 4 + j;
    float y = (vv[j] - mean) * inv * (1.0f + scp[idx]) + shp[idx];
    op[j] = f2bf(y);
  }
  ((ushort4*)(out + (size_t)row * DMODEL))[tid] = ov;
}

// ---------------- banded attention via MFMA: one wave per (b,h,qblock of 32) -----
__launch_bounds__(256)
__global__ void attn_mfma(const ushort_t* __restrict__ qkv, ushort_t* __restrict__ out) {
  const int l = threadIdx.x & 63;
  const int widx = blockIdx.x * 4 + (threadIdx.x >> 6);   // 0..4095
  const int qblk = widx & 63;
  const int bh = widx >> 6;
  const int h = bh & 15;
  const int b = bh >> 4;
  const int q0 = qblk * 32;
  int k0 = q0 - 16;
  if (k0 < 0) k0 = 0;
  if (k0 > S_LEN - 64) k0 = S_LEN - 64;
  const int lr = l & 15;
  const int g = l >> 4;

  const char* base = (const char*)qkv;   // row (s*4+b) stride 6144 B; K at +2048B, V at +4096B

  bf16x8 qf[2][2], kf[4][2];
#pragma unroll
  for (int nt = 0; nt < 2; nt++) {
    size_t rowb = (size_t)((q0 + 16 * nt + lr) * 4 + b) * 6144 + h * 128 + 16 * g;
#pragma unroll
    for (int ks = 0; ks < 2; ks++)
      qf[nt][ks] = *(const bf16x8*)(base + rowb + 64 * ks);
  }
#pragma unroll
  for (int mt = 0; mt < 4; mt++) {
    size_t rowb = (size_t)((k0 + 16 * mt + lr) * 4 + b) * 6144 + 2048 + h * 128 + 16 * g;
#pragma unroll
    for (int ks = 0; ks < 2; ks++)
      kf[mt][ks] = *(const bf16x8*)(base + rowb + 64 * ks);
  }

  f32x4 acc[4][2] = {};
  __builtin_amdgcn_s_setprio(1);
#pragma unroll
  for (int mt = 0; mt < 4; mt++)
#pragma unroll
    for (int nt = 0; nt < 2; nt++)
#pragma unroll
      for (int ks = 0; ks < 2; ks++)
        mfma16(acc[mt][nt], kf[mt][ks], qf[nt][ks]);
  __builtin_amdgcn_s_setprio(0);
  mfma_fence();

  float p0[16], p1[16];
  const int sq0 = q0 + lr, sq1 = q0 + 16 + lr;
  float m0 = -1e30f, m1 = -1e30f;
#pragma unroll
  for (int mt = 0; mt < 4; mt++)
#pragma unroll
    for (int i = 0; i < 4; i++) {
      int sk = k0 + 16 * mt + 4 * g + i;
      int d0 = sq0 - sk, d1 = sq1 - sk;
      float s0 = (d0 <= 16 && d0 >= -16) ? acc[mt][0][i] * 0.125f : -1e30f;
      float s1 = (d1 <= 16 && d1 >= -16) ? acc[mt][1][i] * 0.125f : -1e30f;
      p0[mt * 4 + i] = s0;
      p1[mt * 4 + i] = s1;
      m0 = fmaxf(m0, s0);
      m1 = fmaxf(m1, s1);
    }
  m0 = fmaxf(m0, __shfl_xor(m0, 16, 64));
  m0 = fmaxf(m0, __shfl_xor(m0, 32, 64));
  m1 = fmaxf(m1, __shfl_xor(m1, 16, 64));
  m1 = fmaxf(m1, __shfl_xor(m1, 32, 64));
  float l0 = 0.f, l1 = 0.f;
#pragma unroll
  for (int j = 0; j < 16; j++) {
    float e0 = __expf(p0[j] - m0);
    float e1 = __expf(p1[j] - m1);
    p0[j] = e0; p1[j] = e1;
    l0 += e0; l1 += e1;
  }
  l0 += __shfl_xor(l0, 16, 64); l0 += __shfl_xor(l0, 32, 64);
  l1 += __shfl_xor(l1, 16, 64); l1 += __shfl_xor(l1, 32, 64);
  const float inv0 = 1.0f / l0, inv1 = 1.0f / l1;

  const size_t vb = (size_t)b * 6144 + 4096 + h * 128;
  for (int c = 0; c < 8; c++) {
    float o0[8] = {}, o1[8] = {};
#pragma unroll
    for (int mt = 0; mt < 4; mt++)
#pragma unroll
      for (int i = 0; i < 4; i++) {
        int t = k0 + 16 * mt + 4 * g + i;
        bf16x8 v = *(const bf16x8*)(base + (size_t)t * 24576 + vb + 16 * c);
        float pa = p0[mt * 4 + i], pb = p1[mt * 4 + i];
#pragma unroll
        for (int d = 0; d < 8; d++) {
          float vf = bf2f((unsigned short)v[d]);
          o0[d] += pa * vf;
          o1[d] += pb * vf;
        }
      }
#pragma unroll
    for (int d = 0; d < 8; d++) {
      o0[d] += __shfl_xor(o0[d], 16, 64); o0[d] += __shfl_xor(o0[d], 32, 64);
      o1[d] += __shfl_xor(o1[d], 16, 64); o1[d] += __shfl_xor(o1[d], 32, 64);
    }
    if (g < 2) {   // lanes 0..31 write: q = lr + 16*g, chunk c
      int sq = q0 + 16 * g + lr;
      bf16x8 ov;
#pragma unroll
      for (int d = 0; d < 8; d++) {
        float val = (g ? o1[d] : o0[d]) * (g ? inv1 : inv0);
        ov[d] = (short)f2bf(val);
      }
      *(bf16x8*)((char*)out + (size_t)(sq * 4 + b) * 2048 + h * 128 + c * 16) = ov;
    }
  }
}

// ------------- 8-wave bf16 MFMA GEMM: C[M,N] = A[M,K] @ W[N,K]^T (+epilogue) ------
// R12 dataflow (proven correct) with the T4 fix: ALL of tile t+1's stage loads
// are BURST-issued right after the tile-boundary barrier, so the next
// boundary's vmcnt(0) waits on loads issued one full tile of MFMA (~2500 cy)
// earlier -- R12 spread them through the phases, leaving the newest only
// ~300 cy old and stalling every tile. Safety identical to R12: the single
// barrier separates tile t-1's readers of buf[cur^1] (ds_reads lgkm-complete
// before their last MFMA) from tile t+1's stages into it; vmcnt-before-barrier
// publishes buf[cur]. BM=256, BN in {256,128}, BK=64, 8 waves, per-wave output
// 128 x BN/4 (acc[8][NT]); conflict-free chunk-XOR swizzle (R7-verified).
// EPI 0: out bf16 = acc + bias ; 1: +relu ; 2: out f32 = res + gmod*(acc+bias)
template <int EPI, int K, int BN>
__launch_bounds__(512, 1)
__global__ void gemm8(const ushort_t* __restrict__ A, const ushort_t* __restrict__ W,
                      const float* __restrict__ bias, const float* __restrict__ res,
                      const float* __restrict__ gmod, void* __restrict__ outp,
                      int M, int N) {
  constexpr int NT = BN / 64;                      // n-tiles per wave (4 or 2)
  __shared__ alignas(16) ushort_t As[2][256 * 64]; // 2 x 32 KB
  __shared__ alignas(16) ushort_t Bs[2][BN * 64];  // 2 x 32|16 KB
  const int tid = threadIdx.x;   // 0..511
  const int w = tid >> 6;        // 0..7
  const int l = tid & 63;
  const int wr = w >> 2;         // 0..1  (row half)
  const int wn = w & 3;          // 0..3  (col quarter)

  // XCD-aware bijective remap
  int bx = blockIdx.x, by = blockIdx.y;
  {
    const int nbx = gridDim.x;
    const int nwg = nbx * gridDim.y;
    if ((nwg & 7) == 0) {
      int lin = by * nbx + bx;
      int nlin = (lin & 7) * (nwg >> 3) + (lin >> 3);
      bx = nlin % nbx;
      by = nlin / nbx;
    }
  }
  const int row0 = by * 256;
  const int col0 = bx * BN;

  f32x4 acc[8][NT] = {};

  // staging: round r covers rows r*64 + (tid>>3), chunk tid&7, LDS byte
  // r*8192 + tid*16; source chunk XOR-swizzled (row&7 == (tid>>3)&7 invariant).
  const int srow = tid >> 3;                        // 0..63
  const int scc = (((tid & 7) ^ (srow & 7)) << 3);  // bf16 column
  const ushort_t* ga = A + (size_t)(row0 + srow) * K + scc;
  const ushort_t* gb = W + (size_t)(col0 + srow) * K + scc;
  const int ldst = w * 1024;   // wave-uniform base; HW adds lane*16 -> tid*16

  // read offsets
  const int lrow = l & 15;
  const int g = l >> 4;
  const int cx0 = ((g ^ (lrow & 7)) << 4);          // kk=0
  const int cx1 = (((4 + g) ^ (lrow & 7)) << 4);    // kk=1
  const int abase = (wr * 128 + lrow) * 128;        // + m*2048 + cx
  const int bbase = (wn * (BN / 4) + lrow) * 128;   // + n*2048 + cx

  const int nk = K >> 6;
  // prologue: stage tile 0 into buf 0
  {
    char* lA = (char*)As[0] + ldst;
    char* lB = (char*)Bs[0] + ldst;
#pragma unroll
    for (int r = 0; r < 4; r++) async16(ga + (size_t)(64 * r) * K, lA + r * 8192);
#pragma unroll
    for (int r = 0; r < NT; r++) async16(gb + (size_t)(64 * r) * K, lB + r * 8192);
    ga += 64;
    gb += 64;
  }
  int cur = 0;
  for (int it = 0; it < nk; ++it) {
    asm volatile("s_waitcnt vmcnt(0)" ::: "memory");   // tile it's loads (issued ~1 tile ago) landed
    __builtin_amdgcn_sched_barrier(0);
    __builtin_amdgcn_s_barrier();   // all waves: loads landed + done reading buf[cur^1]
    __builtin_amdgcn_sched_barrier(0);
    if (it + 1 < nk) {   // BURST: stage all of tile it+1 now -> full tile of latency hiding
      char* lA = (char*)As[cur ^ 1] + ldst;
      char* lB = (char*)Bs[cur ^ 1] + ldst;
#pragma unroll
      for (int r = 0; r < 4; r++) async16(ga + (size_t)(64 * r) * K, lA + r * 8192);
#pragma unroll
      for (int r = 0; r < NT; r++) async16(gb + (size_t)(64 * r) * K, lB + r * 8192);
      ga += 64;
      gb += 64;
    }
    const char* Ab = (const char*)As[cur];
    const char* Bb = (const char*)Bs[cur];
    bf16x8 bfr[2][NT];
#pragma unroll
    for (int ph = 0; ph < 4; ph++) {
      const int qm = ph >> 1, kk = ph & 1;
      const int cx = kk ? cx1 : cx0;
      if (qm == 0) {   // B frags for this kk, reused at qm=1
#pragma unroll
        for (int n = 0; n < NT; n++)
          bfr[kk][n] = *(const bf16x8*)(Bb + bbase + n * 2048 + cx);
      }
      bf16x8 afr[4];
#pragma unroll
      for (int m = 0; m < 4; m++)
        afr[m] = *(const bf16x8*)(Ab + abase + (qm * 4 + m) * 2048 + cx);
      __builtin_amdgcn_s_setprio(1);
#pragma unroll
      for (int m = 0; m < 4; m++)
#pragma unroll
        for (int n = 0; n < NT; n++)
          mfma16(acc[qm * 4 + m][n], afr[m], bfr[kk][n]);
      __builtin_amdgcn_s_setprio(0);
    }
    cur ^= 1;
  }
  mfma_fence();

  const int crow = row0 + wr * 128 + g * 4;
  const int ccol = col0 + wn * (BN / 4) + lrow;
#pragma unroll
  for (int m = 0; m < 8; m++) {
#pragma unroll
    for (int i = 0; i < 4; i++) {
      int grow = crow + m * 16 + i;
#pragma unroll
      for (int n = 0; n < NT; n++) {
        int gcol = ccol + n * 16;
        float v = acc[m][n][i] + bias[gcol];
        if constexpr (EPI == 0) {
          ((ushort_t*)outp)[(size_t)grow * N + gcol] = f2bf(v);
        } else if constexpr (EPI == 1) {
          ((ushort_t*)outp)[(size_t)grow * N + gcol] = f2bf(v > 0.f ? v : 0.f);
        } else {
          int bb = grow & 3;
          ((float*)outp)[(size_t)grow * N + gcol] =
              res[(size_t)grow * N + gcol] + gmod[bb * MOD6 + gcol] * v;
        }
      }
    }
  }
}

extern "C" void kernel_launch(void* const* d_in, const int* in_sizes, int n_in,
                              void* d_out, int out_size, void* d_ws, size_t ws_size,
                              hipStream_t stream) {
  const float* x     = (const float*)d_in[0];
  const float* c     = (const float*)d_in[1];
  const float* ada_w = (const float*)d_in[2];
  const float* ada_b = (const float*)d_in[3];
  const float* in_w  = (const float*)d_in[4];
  const float* in_b  = (const float*)d_in[5];
  const float* out_w = (const float*)d_in[6];
  const float* out_b = (const float*)d_in[7];
  const float* w1    = (const float*)d_in[8];
  const float* b1    = (const float*)d_in[9];
  const float* w2    = (const float*)d_in[10];
  const float* b2    = (const float*)d_in[11];

  char* ws = (char*)d_ws;
  float* mod    = (float*)ws;                       //      98,304 B  [B,6D] fp32
  ushort_t* wq  = (ushort_t*)(ws + 98304);          //   6,291,456 B  in_proj bf16
  ushort_t* wo  = (ushort_t*)(ws + 6389760);        //   2,097,152 B  out_proj bf16
  ushort_t* wm1 = (ushort_t*)(ws + 8486912);        //   8,388,608 B  mlp_w1 bf16
  ushort_t* wm2 = (ushort_t*)(ws + 16875520);       //   8,388,608 B  mlp_w2 bf16
  ushort_t* xm  = (ushort_t*)(ws + 25264128);       //  16,777,216 B  LN out bf16
  ushort_t* qkv = (ushort_t*)(ws + 42041344);       //  50,331,648 B  qkv bf16
  ushort_t* att = (ushort_t*)(ws + 92372992);       //  16,777,216 B  attn out bf16
  ushort_t* h   = (ushort_t*)(ws + 42041344);       //  67,108,864 B  (reuses qkv+att)
  float* x1 = (float*)d_out;                        //  x1 lives in d_out

  // all four weight casts in one launch
  castk_all<<<(N4_ALL + 255) / 256, 256, 0, stream>>>(
      (const float4*)in_w, (const float4*)out_w, (const float4*)w1, (const float4*)w2,
      (ushort4*)wq, (ushort4*)wo, (ushort4*)wm1, (ushort4*)wm2);

  ada_k<<<MOD6, 256, 0, stream>>>(c, ada_w, ada_b, mod);

  // xm = LN(x)*(1+sc_msa)+sh_msa
  ln_mod<<<MROWS, 256, 0, stream>>>(x, mod, 0, 1024, xm);
  // qkv = xm @ in_proj_w^T + in_proj_b
  gemm8<0, 1024, 256><<<dim3(3072 / 256, MROWS / 256), 512, 0, stream>>>(xm, wq, in_b, nullptr, nullptr, qkv, MROWS, 3072);
  // windowed attention (MFMA banded, one wave per (b,h,32-query block))
  attn_mfma<<<(BATCH * NHEAD * (S_LEN / 32)) / 4, 256, 0, stream>>>(qkv, att);
  // x1 = x + g_msa * (att @ out_proj_w^T + out_proj_b)
  gemm8<2, 1024, 128><<<dim3(1024 / 128, MROWS / 256), 512, 0, stream>>>(att, wo, out_b, x, mod + 2 * DMODEL, x1, MROWS, 1024);
  // xm = LN(x1)*(1+sc_mlp)+sh_mlp
  ln_mod<<<MROWS, 256, 0, stream>>>(x1, mod, 3 * DMODEL, 4 * DMODEL, xm);
  // h = relu(xm @ mlp_w1^T + mlp_b1)
  gemm8<1, 1024, 256><<<dim3(4096 / 256, MROWS / 256), 512, 0, stream>>>(xm, wm1, b1, nullptr, nullptr, h, MROWS, 4096);
  // out = x1 + g_mlp * (h @ mlp_w2^T + mlp_b2)
  gemm8<2, 4096, 128><<<dim3(1024 / 128, MROWS / 256), 512, 0, stream>>>(h, wm2, b2, x1, mod + 5 * DMODEL, (float*)d_out, MROWS, 1024);
}

// Round 16
// 318.217 us; speedup vs baseline: 1.0981x; 1.0981x over previous
//
#include <hip/hip_runtime.h>

#define S_LEN 2048
#define BATCH 4
#define DMODEL 1024
#define NHEAD 16
#define MROWS (S_LEN * BATCH)   // 8192
#define MOD6 (6 * DMODEL)       // 6144

typedef float f32x4 __attribute__((ext_vector_type(4)));
typedef short bf16x8 __attribute__((ext_vector_type(8)));
typedef unsigned short ushort_t;

__device__ __forceinline__ unsigned short f2bf(float f) {
  unsigned u = __float_as_uint(f);
  u += 0x7FFF + ((u >> 16) & 1);   // round-to-nearest-even
  return (unsigned short)(u >> 16);
}
__device__ __forceinline__ float bf2f(unsigned short h) {
  return __uint_as_float(((unsigned)h) << 16);
}
__device__ __forceinline__ float wave_sum(float v) {
#pragma unroll
  for (int off = 32; off > 0; off >>= 1) v += __shfl_xor(v, off, 64);
  return v;
}
__device__ __forceinline__ void mfma16(f32x4& c, bf16x8 a, bf16x8 b) {
  asm volatile("v_mfma_f32_16x16x32_bf16 %0, %1, %2, %0" : "+v"(c) : "v"(a), "v"(b));
}
// Fence between MFMA writes and VALU reads of acc: sched_barrier pins all code
// motion; 24 wait-states cover the MFMA->VALU RAW hazard window.
__device__ __forceinline__ void mfma_fence() {
  __builtin_amdgcn_sched_barrier(0);
  asm volatile("s_nop 7\n\ts_nop 7\n\ts_nop 7");
  __builtin_amdgcn_sched_barrier(0);
}
__device__ __forceinline__ void async16(const void* g, void* l) {
  __builtin_amdgcn_global_load_lds((const __attribute__((address_space(1))) void*)g,
                                   (__attribute__((address_space(3))) void*)l, 16, 0, 0);
}

// ---------------- fused weight cast fp32 -> bf16 (all four weights, one launch) ----
#define N4_INW  786432          // 3072*1024/4
#define N4_OUTW 262144          // 1024*1024/4
#define N4_W1   1048576         // 4096*1024/4
#define N4_W2   1048576         // 1024*4096/4
#define N4_ALL  (N4_INW + N4_OUTW + N4_W1 + N4_W2)
__launch_bounds__(256)
__global__ void castk_all(const float4* __restrict__ inw, const float4* __restrict__ outw,
                          const float4* __restrict__ w1, const float4* __restrict__ w2,
                          ushort4* __restrict__ dq, ushort4* __restrict__ dow,
                          ushort4* __restrict__ dw1, ushort4* __restrict__ dw2) {
  int i = blockIdx.x * 256 + threadIdx.x;
  if (i >= N4_ALL) return;
  const float4* src;
  ushort4* dst;
  int j = i;
  if (j < N4_INW) { src = inw; dst = dq; }
  else if ((j -= N4_INW) < N4_OUTW) { src = outw; dst = dow; }
  else if ((j -= N4_OUTW) < N4_W1) { src = w1; dst = dw1; }
  else { j -= N4_W1; src = w2; dst = dw2; }
  float4 v = src[j];
  ushort4 o;
  o.x = f2bf(v.x); o.y = f2bf(v.y); o.z = f2bf(v.z); o.w = f2bf(v.w);
  dst[j] = o;
}

// ---------------- mod = relu(c) @ ada_w.T + ada_b : [B, 6D] fp32 ----------------
__launch_bounds__(256)
__global__ void ada_k(const float* __restrict__ c, const float* __restrict__ aw,
                      const float* __restrict__ ab, float* __restrict__ mod) {
  int j = blockIdx.x;           // 0..6143
  int b = threadIdx.x >> 6;     // wave -> batch
  int l = threadIdx.x & 63;
  const float* wrow = aw + (size_t)j * DMODEL;
  const float* crow = c + b * DMODEL;
  float s = 0.f;
#pragma unroll 4
  for (int i = l; i < DMODEL; i += 64) {
    float cv = crow[i];
    cv = cv > 0.f ? cv : 0.f;
    s += cv * wrow[i];
  }
  s = wave_sum(s);
  if (l == 0) mod[b * MOD6 + j] = s + ab[j];
}

// ---------------- LN + AdaLN modulate -> bf16 ----------------
__launch_bounds__(256)
__global__ void ln_mod(const float* __restrict__ x, const float* __restrict__ mod,
                       int sh_off, int sc_off, ushort_t* __restrict__ out) {
  __shared__ float red[8];
  int row = blockIdx.x;         // s*B + b
  int b = row & 3;
  int tid = threadIdx.x;
  const float4* xr = (const float4*)(x + (size_t)row * DMODEL);
  float4 v = xr[tid];
  float s = v.x + v.y + v.z + v.w;
  float s2 = v.x * v.x + v.y * v.y + v.z * v.z + v.w * v.w;
  s = wave_sum(s);
  s2 = wave_sum(s2);
  int w = tid >> 6, l = tid & 63;
  if (l == 0) { red[w] = s; red[4 + w] = s2; }
  __syncthreads();
  s = red[0] + red[1] + red[2] + red[3];
  s2 = red[4] + red[5] + red[6] + red[7];
  float mean = s * (1.0f / DMODEL);
  float var = s2 * (1.0f / DMODEL) - mean * mean;
  float inv = rsqrtf(var + 1e-6f);
  const float* shp = mod + b * MOD6 + sh_off;
  const float* scp = mod + b * MOD6 + sc_off;
  float vv[4] = {v.x, v.y, v.z, v.w};
  ushort4 ov;
  ushort_t* op = (ushort_t*)&ov;
#pragma unroll
  for (int j = 0; j < 4; j++) {
    int idx = tid * 4 + j;
    float y = (vv[j] - mean) * inv * (1.0f + scp[idx]) + shp[idx];
    op[j] = f2bf(y);
  }
  ((ushort4*)(out + (size_t)row * DMODEL))[tid] = ov;
}

// ---------------- banded attention via MFMA: one wave per (b,h,qblock of 32) -----
__launch_bounds__(256)
__global__ void attn_mfma(const ushort_t* __restrict__ qkv, ushort_t* __restrict__ out) {
  const int l = threadIdx.x & 63;
  const int widx = blockIdx.x * 4 + (threadIdx.x >> 6);   // 0..4095
  const int qblk = widx & 63;
  const int bh = widx >> 6;
  const int h = bh & 15;
  const int b = bh >> 4;
  const int q0 = qblk * 32;
  int k0 = q0 - 16;
  if (k0 < 0) k0 = 0;
  if (k0 > S_LEN - 64) k0 = S_LEN - 64;
  const int lr = l & 15;
  const int g = l >> 4;

  const char* base = (const char*)qkv;   // row (s*4+b) stride 6144 B; K at +2048B, V at +4096B

  bf16x8 qf[2][2], kf[4][2];
#pragma unroll
  for (int nt = 0; nt < 2; nt++) {
    size_t rowb = (size_t)((q0 + 16 * nt + lr) * 4 + b) * 6144 + h * 128 + 16 * g;
#pragma unroll
    for (int ks = 0; ks < 2; ks++)
      qf[nt][ks] = *(const bf16x8*)(base + rowb + 64 * ks);
  }
#pragma unroll
  for (int mt = 0; mt < 4; mt++) {
    size_t rowb = (size_t)((k0 + 16 * mt + lr) * 4 + b) * 6144 + 2048 + h * 128 + 16 * g;
#pragma unroll
    for (int ks = 0; ks < 2; ks++)
      kf[mt][ks] = *(const bf16x8*)(base + rowb + 64 * ks);
  }

  f32x4 acc[4][2] = {};
  __builtin_amdgcn_s_setprio(1);
#pragma unroll
  for (int mt = 0; mt < 4; mt++)
#pragma unroll
    for (int nt = 0; nt < 2; nt++)
#pragma unroll
      for (int ks = 0; ks < 2; ks++)
        mfma16(acc[mt][nt], kf[mt][ks], qf[nt][ks]);
  __builtin_amdgcn_s_setprio(0);
  mfma_fence();

  float p0[16], p1[16];
  const int sq0 = q0 + lr, sq1 = q0 + 16 + lr;
  float m0 = -1e30f, m1 = -1e30f;
#pragma unroll
  for (int mt = 0; mt < 4; mt++)
#pragma unroll
    for (int i = 0; i < 4; i++) {
      int sk = k0 + 16 * mt + 4 * g + i;
      int d0 = sq0 - sk, d1 = sq1 - sk;
      float s0 = (d0 <= 16 && d0 >= -16) ? acc[mt][0][i] * 0.125f : -1e30f;
      float s1 = (d1 <= 16 && d1 >= -16) ? acc[mt][1][i] * 0.125f : -1e30f;
      p0[mt * 4 + i] = s0;
      p1[mt * 4 + i] = s1;
      m0 = fmaxf(m0, s0);
      m1 = fmaxf(m1, s1);
    }
  m0 = fmaxf(m0, __shfl_xor(m0, 16, 64));
  m0 = fmaxf(m0, __shfl_xor(m0, 32, 64));
  m1 = fmaxf(m1, __shfl_xor(m1, 16, 64));
  m1 = fmaxf(m1, __shfl_xor(m1, 32, 64));
  float l0 = 0.f, l1 = 0.f;
#pragma unroll
  for (int j = 0; j < 16; j++) {
    float e0 = __expf(p0[j] - m0);
    float e1 = __expf(p1[j] - m1);
    p0[j] = e0; p1[j] = e1;
    l0 += e0; l1 += e1;
  }
  l0 += __shfl_xor(l0, 16, 64); l0 += __shfl_xor(l0, 32, 64);
  l1 += __shfl_xor(l1, 16, 64); l1 += __shfl_xor(l1, 32, 64);
  const float inv0 = 1.0f / l0, inv1 = 1.0f / l1;

  const size_t vb = (size_t)b * 6144 + 4096 + h * 128;
  for (int c = 0; c < 8; c++) {
    float o0[8] = {}, o1[8] = {};
#pragma unroll
    for (int mt = 0; mt < 4; mt++)
#pragma unroll
      for (int i = 0; i < 4; i++) {
        int t = k0 + 16 * mt + 4 * g + i;
        bf16x8 v = *(const bf16x8*)(base + (size_t)t * 24576 + vb + 16 * c);
        float pa = p0[mt * 4 + i], pb = p1[mt * 4 + i];
#pragma unroll
        for (int d = 0; d < 8; d++) {
          float vf = bf2f((unsigned short)v[d]);
          o0[d] += pa * vf;
          o1[d] += pb * vf;
        }
      }
#pragma unroll
    for (int d = 0; d < 8; d++) {
      o0[d] += __shfl_xor(o0[d], 16, 64); o0[d] += __shfl_xor(o0[d], 32, 64);
      o1[d] += __shfl_xor(o1[d], 16, 64); o1[d] += __shfl_xor(o1[d], 32, 64);
    }
    if (g < 2) {   // lanes 0..31 write: q = lr + 16*g, chunk c
      int sq = q0 + 16 * g + lr;
      bf16x8 ov;
#pragma unroll
      for (int d = 0; d < 8; d++) {
        float val = (g ? o1[d] : o0[d]) * (g ? inv1 : inv0);
        ov[d] = (short)f2bf(val);
      }
      *(bf16x8*)((char*)out + (size_t)(sq * 4 + b) * 2048 + h * 128 + c * 16) = ov;
    }
  }
}

// ---------------- bf16 MFMA GEMM: C[M,N] = A[M,K] @ W[N,K]^T (+epilogue) ----------
// R13-verified kernel (session best: 318.6 us total; MLP-class 79 us,
// MfmaUtil ~34%, 0 bank conflicts, occupancy ~35%, no spills): 128x128 tile,
// BK=64 single-buffered LDS, conflict-free chunk-XOR swizzle, K template
// constant, __launch_bounds__(256,4), XCD-bijective chunk remap.
// R9-R15 restructures (bigger tiles, dbuf, counted vmcnt, 8-wave/4-wave 256^2)
// all regressed or spilled (inline-asm MFMA + spills = hazard corruption).
// EPI 0: out bf16 = acc + bias
// EPI 1: out bf16 = relu(acc + bias)
// EPI 2: out f32  = res + gmod[b,col] * (acc + bias)
template <int EPI, int K>
__launch_bounds__(256, 4)
__global__ void gemm_bt(const ushort_t* __restrict__ A, const ushort_t* __restrict__ W,
                        const float* __restrict__ bias, const float* __restrict__ res,
                        const float* __restrict__ gmod, void* __restrict__ outp,
                        int M, int N) {
  __shared__ alignas(16) ushort_t As[128 * 64];  // 16 KB
  __shared__ alignas(16) ushort_t Bs[128 * 64];  // 16 KB
  const int tid = threadIdx.x;
  const int w = tid >> 6;
  const int l = tid & 63;

  // XCD-aware bijective remap: dispatch-linear -> contiguous chunk per XCD.
  int bx = blockIdx.x, by = blockIdx.y;
  {
    const int nbx = gridDim.x;
    const int nwg = nbx * gridDim.y;
    if ((nwg & 7) == 0) {
      int lin = by * nbx + bx;
      int nlin = (lin & 7) * (nwg >> 3) + (lin >> 3);
      bx = nlin % nbx;
      by = nlin / nbx;
    }
  }
  const int row0 = by * 128;
  const int col0 = bx * 128;
  const int wr = (w >> 1) * 64;
  const int wc = (w & 1) * 64;

  f32x4 acc[4][4] = {};

  // staging: thread tid -> slot (row = tid>>3 + 32r, chunk = tid&7);
  // source global chunk = (tid&7) ^ ((tid>>3)&7)   [row&7 == (tid>>3)&7]
  const int srow = tid >> 3;
  const int scc = (((tid & 7) ^ (srow & 7)) << 3);   // bf16 column
  const ushort_t* ga = A + (size_t)(row0 + srow) * K + scc;
  const ushort_t* gb = W + (size_t)(col0 + srow) * K + scc;
  char* lA = (char*)As + w * 1024;   // wave-uniform; HW adds lane*16; +4096/round
  char* lB = (char*)Bs + w * 1024;

  // read offsets: frag (tile, kk) at row wr|wc + tile*16 + lrow, global chunk kk*4+g
  const int lrow = l & 15;
  const int g = l >> 4;
  const int cx0 = ((g ^ (lrow & 7)) << 4);         // kk=0
  const int cx1 = (((4 + g) ^ (lrow & 7)) << 4);   // kk=1
  const int arow = (wr + lrow) * 128;
  const int brow = (wc + lrow) * 128;

  const int nk = K >> 6;
  for (int it = 0; it < nk; ++it) {
#pragma unroll
    for (int r = 0; r < 4; r++) async16(ga + (size_t)(32 * r) * K, lA + r * 4096);
#pragma unroll
    for (int r = 0; r < 4; r++) async16(gb + (size_t)(32 * r) * K, lB + r * 4096);
    ga += 64;
    gb += 64;
    __syncthreads();   // drains vmcnt: tile staged
#pragma unroll
    for (int kk = 0; kk < 2; kk++) {
      const int cx = kk ? cx1 : cx0;
      bf16x8 afr[4], bfr[4];
#pragma unroll
      for (int m = 0; m < 4; m++) afr[m] = *(const bf16x8*)((char*)As + arow + m * 2048 + cx);
#pragma unroll
      for (int n = 0; n < 4; n++) bfr[n] = *(const bf16x8*)((char*)Bs + brow + n * 2048 + cx);
#pragma unroll
      for (int m = 0; m < 4; m++)
#pragma unroll
        for (int n = 0; n < 4; n++) mfma16(acc[m][n], afr[m], bfr[n]);
    }
    __syncthreads();   // protect buffer reuse
  }
  mfma_fence();

  const int crow = row0 + wr + g * 4;
  const int ccol = col0 + wc + lrow;
#pragma unroll
  for (int m = 0; m < 4; m++) {
#pragma unroll
    for (int i = 0; i < 4; i++) {
      int grow = crow + m * 16 + i;
#pragma unroll
      for (int n = 0; n < 4; n++) {
        int gcol = ccol + n * 16;
        float v = acc[m][n][i] + bias[gcol];
        if constexpr (EPI == 0) {
          ((ushort_t*)outp)[(size_t)grow * N + gcol] = f2bf(v);
        } else if constexpr (EPI == 1) {
          ((ushort_t*)outp)[(size_t)grow * N + gcol] = f2bf(v > 0.f ? v : 0.f);
        } else {
          int bb = grow & 3;
          ((float*)outp)[(size_t)grow * N + gcol] =
              res[(size_t)grow * N + gcol] + gmod[bb * MOD6 + gcol] * v;
        }
      }
    }
  }
}

extern "C" void kernel_launch(void* const* d_in, const int* in_sizes, int n_in,
                              void* d_out, int out_size, void* d_ws, size_t ws_size,
                              hipStream_t stream) {
  const float* x     = (const float*)d_in[0];
  const float* c     = (const float*)d_in[1];
  const float* ada_w = (const float*)d_in[2];
  const float* ada_b = (const float*)d_in[3];
  const float* in_w  = (const float*)d_in[4];
  const float* in_b  = (const float*)d_in[5];
  const float* out_w = (const float*)d_in[6];
  const float* out_b = (const float*)d_in[7];
  const float* w1    = (const float*)d_in[8];
  const float* b1    = (const float*)d_in[9];
  const float* w2    = (const float*)d_in[10];
  const float* b2    = (const float*)d_in[11];

  char* ws = (char*)d_ws;
  float* mod    = (float*)ws;                       //      98,304 B  [B,6D] fp32
  ushort_t* wq  = (ushort_t*)(ws + 98304);          //   6,291,456 B  in_proj bf16
  ushort_t* wo  = (ushort_t*)(ws + 6389760);        //   2,097,152 B  out_proj bf16
  ushort_t* wm1 = (ushort_t*)(ws + 8486912);        //   8,388,608 B  mlp_w1 bf16
  ushort_t* wm2 = (ushort_t*)(ws + 16875520);       //   8,388,608 B  mlp_w2 bf16
  ushort_t* xm  = (ushort_t*)(ws + 25264128);       //  16,777,216 B  LN out bf16
  ushort_t* qkv = (ushort_t*)(ws + 42041344);       //  50,331,648 B  qkv bf16
  ushort_t* att = (ushort_t*)(ws + 92372992);       //  16,777,216 B  attn out bf16
  ushort_t* h   = (ushort_t*)(ws + 42041344);       //  67,108,864 B  (reuses qkv+att)
  float* x1 = (float*)d_out;                        //  x1 lives in d_out

  // all four weight casts in one launch
  castk_all<<<(N4_ALL + 255) / 256, 256, 0, stream>>>(
      (const float4*)in_w, (const float4*)out_w, (const float4*)w1, (const float4*)w2,
      (ushort4*)wq, (ushort4*)wo, (ushort4*)wm1, (ushort4*)wm2);

  ada_k<<<MOD6, 256, 0, stream>>>(c, ada_w, ada_b, mod);

  // xm = LN(x)*(1+sc_msa)+sh_msa
  ln_mod<<<MROWS, 256, 0, stream>>>(x, mod, 0, 1024, xm);
  // qkv = xm @ in_proj_w^T + in_proj_b
  gemm_bt<0, 1024><<<dim3(3072 / 128, MROWS / 128), 256, 0, stream>>>(xm, wq, in_b, nullptr, nullptr, qkv, MROWS, 3072);
  // windowed attention (MFMA banded, one wave per (b,h,32-query block))
  attn_mfma<<<(BATCH * NHEAD * (S_LEN / 32)) / 4, 256, 0, stream>>>(qkv, att);
  // x1 = x + g_msa * (att @ out_proj_w^T + out_proj_b)
  gemm_bt<2, 1024><<<dim3(1024 / 128, MROWS / 128), 256, 0, stream>>>(att, wo, out_b, x, mod + 2 * DMODEL, x1, MROWS, 1024);
  // xm = LN(x1)*(1+sc_mlp)+sh_mlp
  ln_mod<<<MROWS, 256, 0, stream>>>(x1, mod, 3 * DMODEL, 4 * DMODEL, xm);
  // h = relu(xm @ mlp_w1^T + mlp_b1)
  gemm_bt<1, 1024><<<dim3(4096 / 128, MROWS / 128), 256, 0, stream>>>(xm, wm1, b1, nullptr, nullptr, h, MROWS, 4096);
  // out = x1 + g_mlp * (h @ mlp_w2^T + mlp_b2)
  gemm_bt<2, 4096><<<dim3(1024 / 128, MROWS / 128), 256, 0, stream>>>(h, wm2, b2, x1, mod + 5 * DMODEL, (float*)d_out, MROWS, 1024);
}

// Round 17
// 314.924 us; speedup vs baseline: 1.1096x; 1.0105x over previous
//
#include <hip/hip_runtime.h>

#define S_LEN 2048
#define BATCH 4
#define DMODEL 1024
#define NHEAD 16
#define MROWS (S_LEN * BATCH)   // 8192
#define MOD6 (6 * DMODEL)       // 6144

typedef float f32x4 __attribute__((ext_vector_type(4)));
typedef short bf16x8 __attribute__((ext_vector_type(8)));
typedef unsigned short ushort_t;

__device__ __forceinline__ unsigned short f2bf(float f) {
  unsigned u = __float_as_uint(f);
  u += 0x7FFF + ((u >> 16) & 1);   // round-to-nearest-even
  return (unsigned short)(u >> 16);
}
__device__ __forceinline__ float bf2f(unsigned short h) {
  return __uint_as_float(((unsigned)h) << 16);
}
__device__ __forceinline__ float wave_sum(float v) {
#pragma unroll
  for (int off = 32; off > 0; off >>= 1) v += __shfl_xor(v, off, 64);
  return v;
}
__device__ __forceinline__ void mfma16(f32x4& c, bf16x8 a, bf16x8 b) {
  asm volatile("v_mfma_f32_16x16x32_bf16 %0, %1, %2, %0" : "+v"(c) : "v"(a), "v"(b));
}
// Fence between MFMA writes and VALU reads of acc: sched_barrier pins all code
// motion; 24 wait-states cover the MFMA->VALU RAW hazard window.
__device__ __forceinline__ void mfma_fence() {
  __builtin_amdgcn_sched_barrier(0);
  asm volatile("s_nop 7\n\ts_nop 7\n\ts_nop 7");
  __builtin_amdgcn_sched_barrier(0);
}
__device__ __forceinline__ void async16(const void* g, void* l) {
  __builtin_amdgcn_global_load_lds((const __attribute__((address_space(1))) void*)g,
                                   (__attribute__((address_space(3))) void*)l, 16, 0, 0);
}

// ---------------- fused weight cast fp32 -> bf16 (all four weights, one launch) ----
#define N4_INW  786432          // 3072*1024/4
#define N4_OUTW 262144          // 1024*1024/4
#define N4_W1   1048576         // 4096*1024/4
#define N4_W2   1048576         // 1024*4096/4
#define N4_ALL  (N4_INW + N4_OUTW + N4_W1 + N4_W2)
__launch_bounds__(256)
__global__ void castk_all(const float4* __restrict__ inw, const float4* __restrict__ outw,
                          const float4* __restrict__ w1, const float4* __restrict__ w2,
                          ushort4* __restrict__ dq, ushort4* __restrict__ dow,
                          ushort4* __restrict__ dw1, ushort4* __restrict__ dw2) {
  int i = blockIdx.x * 256 + threadIdx.x;
  if (i >= N4_ALL) return;
  const float4* src;
  ushort4* dst;
  int j = i;
  if (j < N4_INW) { src = inw; dst = dq; }
  else if ((j -= N4_INW) < N4_OUTW) { src = outw; dst = dow; }
  else if ((j -= N4_OUTW) < N4_W1) { src = w1; dst = dw1; }
  else { j -= N4_W1; src = w2; dst = dw2; }
  float4 v = src[j];
  ushort4 o;
  o.x = f2bf(v.x); o.y = f2bf(v.y); o.z = f2bf(v.z); o.w = f2bf(v.w);
  dst[j] = o;
}

// ---------------- mod = relu(c) @ ada_w.T + ada_b : [B, 6D] fp32 ----------------
__launch_bounds__(256)
__global__ void ada_k(const float* __restrict__ c, const float* __restrict__ aw,
                      const float* __restrict__ ab, float* __restrict__ mod) {
  int j = blockIdx.x;           // 0..6143
  int b = threadIdx.x >> 6;     // wave -> batch
  int l = threadIdx.x & 63;
  const float* wrow = aw + (size_t)j * DMODEL;
  const float* crow = c + b * DMODEL;
  float s = 0.f;
#pragma unroll 4
  for (int i = l; i < DMODEL; i += 64) {
    float cv = crow[i];
    cv = cv > 0.f ? cv : 0.f;
    s += cv * wrow[i];
  }
  s = wave_sum(s);
  if (l == 0) mod[b * MOD6 + j] = s + ab[j];
}

// ---------------- LN + AdaLN modulate -> bf16 (f32 or bf16 input) ----------------
template <int BF16IN>
__launch_bounds__(256)
__global__ void ln_mod(const void* __restrict__ xin, const float* __restrict__ mod,
                       int sh_off, int sc_off, ushort_t* __restrict__ out) {
  __shared__ float red[8];
  int row = blockIdx.x;         // s*B + b
  int b = row & 3;
  int tid = threadIdx.x;
  float vv[4];
  if constexpr (BF16IN) {
    ushort4 v4 = ((const ushort4*)((const ushort_t*)xin + (size_t)row * DMODEL))[tid];
    vv[0] = bf2f(v4.x); vv[1] = bf2f(v4.y); vv[2] = bf2f(v4.z); vv[3] = bf2f(v4.w);
  } else {
    float4 v = ((const float4*)((const float*)xin + (size_t)row * DMODEL))[tid];
    vv[0] = v.x; vv[1] = v.y; vv[2] = v.z; vv[3] = v.w;
  }
  float s = vv[0] + vv[1] + vv[2] + vv[3];
  float s2 = vv[0] * vv[0] + vv[1] * vv[1] + vv[2] * vv[2] + vv[3] * vv[3];
  s = wave_sum(s);
  s2 = wave_sum(s2);
  int w = tid >> 6, l = tid & 63;
  if (l == 0) { red[w] = s; red[4 + w] = s2; }
  __syncthreads();
  s = red[0] + red[1] + red[2] + red[3];
  s2 = red[4] + red[5] + red[6] + red[7];
  float mean = s * (1.0f / DMODEL);
  float var = s2 * (1.0f / DMODEL) - mean * mean;
  float inv = rsqrtf(var + 1e-6f);
  const float* shp = mod + b * MOD6 + sh_off;
  const float* scp = mod + b * MOD6 + sc_off;
  ushort4 ov;
  ushort_t* op = (ushort_t*)&ov;
#pragma unroll
  for (int j = 0; j < 4; j++) {
    int idx = tid * 4 + j;
    float y = (vv[j] - mean) * inv * (1.0f + scp[idx]) + shp[idx];
    op[j] = f2bf(y);
  }
  ((ushort4*)(out + (size_t)row * DMODEL))[tid] = ov;
}

// ---------------- banded attention via MFMA: one wave per (b,h,qblock of 32) -----
__launch_bounds__(256)
__global__ void attn_mfma(const ushort_t* __restrict__ qkv, ushort_t* __restrict__ out) {
  const int l = threadIdx.x & 63;
  const int widx = blockIdx.x * 4 + (threadIdx.x >> 6);   // 0..4095
  const int qblk = widx & 63;
  const int bh = widx >> 6;
  const int h = bh & 15;
  const int b = bh >> 4;
  const int q0 = qblk * 32;
  int k0 = q0 - 16;
  if (k0 < 0) k0 = 0;
  if (k0 > S_LEN - 64) k0 = S_LEN - 64;
  const int lr = l & 15;
  const int g = l >> 4;

  const char* base = (const char*)qkv;   // row (s*4+b) stride 6144 B; K at +2048B, V at +4096B

  bf16x8 qf[2][2], kf[4][2];
#pragma unroll
  for (int nt = 0; nt < 2; nt++) {
    size_t rowb = (size_t)((q0 + 16 * nt + lr) * 4 + b) * 6144 + h * 128 + 16 * g;
#pragma unroll
    for (int ks = 0; ks < 2; ks++)
      qf[nt][ks] = *(const bf16x8*)(base + rowb + 64 * ks);
  }
#pragma unroll
  for (int mt = 0; mt < 4; mt++) {
    size_t rowb = (size_t)((k0 + 16 * mt + lr) * 4 + b) * 6144 + 2048 + h * 128 + 16 * g;
#pragma unroll
    for (int ks = 0; ks < 2; ks++)
      kf[mt][ks] = *(const bf16x8*)(base + rowb + 64 * ks);
  }

  f32x4 acc[4][2] = {};
  __builtin_amdgcn_s_setprio(1);
#pragma unroll
  for (int mt = 0; mt < 4; mt++)
#pragma unroll
    for (int nt = 0; nt < 2; nt++)
#pragma unroll
      for (int ks = 0; ks < 2; ks++)
        mfma16(acc[mt][nt], kf[mt][ks], qf[nt][ks]);
  __builtin_amdgcn_s_setprio(0);
  mfma_fence();

  float p0[16], p1[16];
  const int sq0 = q0 + lr, sq1 = q0 + 16 + lr;
  float m0 = -1e30f, m1 = -1e30f;
#pragma unroll
  for (int mt = 0; mt < 4; mt++)
#pragma unroll
    for (int i = 0; i < 4; i++) {
      int sk = k0 + 16 * mt + 4 * g + i;
      int d0 = sq0 - sk, d1 = sq1 - sk;
      float s0 = (d0 <= 16 && d0 >= -16) ? acc[mt][0][i] * 0.125f : -1e30f;
      float s1 = (d1 <= 16 && d1 >= -16) ? acc[mt][1][i] * 0.125f : -1e30f;
      p0[mt * 4 + i] = s0;
      p1[mt * 4 + i] = s1;
      m0 = fmaxf(m0, s0);
      m1 = fmaxf(m1, s1);
    }
  m0 = fmaxf(m0, __shfl_xor(m0, 16, 64));
  m0 = fmaxf(m0, __shfl_xor(m0, 32, 64));
  m1 = fmaxf(m1, __shfl_xor(m1, 16, 64));
  m1 = fmaxf(m1, __shfl_xor(m1, 32, 64));
  float l0 = 0.f, l1 = 0.f;
#pragma unroll
  for (int j = 0; j < 16; j++) {
    float e0 = __expf(p0[j] - m0);
    float e1 = __expf(p1[j] - m1);
    p0[j] = e0; p1[j] = e1;
    l0 += e0; l1 += e1;
  }
  l0 += __shfl_xor(l0, 16, 64); l0 += __shfl_xor(l0, 32, 64);
  l1 += __shfl_xor(l1, 16, 64); l1 += __shfl_xor(l1, 32, 64);
  const float inv0 = 1.0f / l0, inv1 = 1.0f / l1;

  const size_t vb = (size_t)b * 6144 + 4096 + h * 128;
  for (int c = 0; c < 8; c++) {
    float o0[8] = {}, o1[8] = {};
#pragma unroll
    for (int mt = 0; mt < 4; mt++)
#pragma unroll
      for (int i = 0; i < 4; i++) {
        int t = k0 + 16 * mt + 4 * g + i;
        bf16x8 v = *(const bf16x8*)(base + (size_t)t * 24576 + vb + 16 * c);
        float pa = p0[mt * 4 + i], pb = p1[mt * 4 + i];
#pragma unroll
        for (int d = 0; d < 8; d++) {
          float vf = bf2f((unsigned short)v[d]);
          o0[d] += pa * vf;
          o1[d] += pb * vf;
        }
      }
#pragma unroll
    for (int d = 0; d < 8; d++) {
      o0[d] += __shfl_xor(o0[d], 16, 64); o0[d] += __shfl_xor(o0[d], 32, 64);
      o1[d] += __shfl_xor(o1[d], 16, 64); o1[d] += __shfl_xor(o1[d], 32, 64);
    }
    if (g < 2) {   // lanes 0..31 write: q = lr + 16*g, chunk c
      int sq = q0 + 16 * g + lr;
      bf16x8 ov;
#pragma unroll
      for (int d = 0; d < 8; d++) {
        float val = (g ? o1[d] : o0[d]) * (g ? inv1 : inv0);
        ov[d] = (short)f2bf(val);
      }
      *(bf16x8*)((char*)out + (size_t)(sq * 4 + b) * 2048 + h * 128 + c * 16) = ov;
    }
  }
}

// ---------------- bf16 MFMA GEMM: C[M,N] = A[M,K] @ W[N,K]^T (+epilogue) ----------
// R13/R16-verified kernel (session best: 318.2 us total; MLP-class 79 us,
// MfmaUtil ~35%, 0 bank conflicts, occupancy ~35%, no spills).
// EPI 0: out bf16 = acc + bias
// EPI 1: out bf16 = relu(acc + bias)
// EPI 2: out f32  = res_f32  + gmod[b,col] * (acc + bias)
// EPI 3: out bf16 = res_f32  + gmod[b,col] * (acc + bias)
// EPI 4: out f32  = res_bf16 + gmod[b,col] * (acc + bias)
template <int EPI, int K>
__launch_bounds__(256, 4)
__global__ void gemm_bt(const ushort_t* __restrict__ A, const ushort_t* __restrict__ W,
                        const float* __restrict__ bias, const float* __restrict__ res,
                        const float* __restrict__ gmod, void* __restrict__ outp,
                        int M, int N) {
  __shared__ alignas(16) ushort_t As[128 * 64];  // 16 KB
  __shared__ alignas(16) ushort_t Bs[128 * 64];  // 16 KB
  const int tid = threadIdx.x;
  const int w = tid >> 6;
  const int l = tid & 63;

  // XCD-aware bijective remap: dispatch-linear -> contiguous chunk per XCD.
  int bx = blockIdx.x, by = blockIdx.y;
  {
    const int nbx = gridDim.x;
    const int nwg = nbx * gridDim.y;
    if ((nwg & 7) == 0) {
      int lin = by * nbx + bx;
      int nlin = (lin & 7) * (nwg >> 3) + (lin >> 3);
      bx = nlin % nbx;
      by = nlin / nbx;
    }
  }
  const int row0 = by * 128;
  const int col0 = bx * 128;
  const int wr = (w >> 1) * 64;
  const int wc = (w & 1) * 64;

  f32x4 acc[4][4] = {};

  // staging: thread tid -> slot (row = tid>>3 + 32r, chunk = tid&7);
  // source global chunk = (tid&7) ^ ((tid>>3)&7)   [row&7 == (tid>>3)&7]
  const int srow = tid >> 3;
  const int scc = (((tid & 7) ^ (srow & 7)) << 3);   // bf16 column
  const ushort_t* ga = A + (size_t)(row0 + srow) * K + scc;
  const ushort_t* gb = W + (size_t)(col0 + srow) * K + scc;
  char* lA = (char*)As + w * 1024;   // wave-uniform; HW adds lane*16; +4096/round
  char* lB = (char*)Bs + w * 1024;

  // read offsets: frag (tile, kk) at row wr|wc + tile*16 + lrow, global chunk kk*4+g
  const int lrow = l & 15;
  const int g = l >> 4;
  const int cx0 = ((g ^ (lrow & 7)) << 4);         // kk=0
  const int cx1 = (((4 + g) ^ (lrow & 7)) << 4);   // kk=1
  const int arow = (wr + lrow) * 128;
  const int brow = (wc + lrow) * 128;

  const int nk = K >> 6;
  for (int it = 0; it < nk; ++it) {
#pragma unroll
    for (int r = 0; r < 4; r++) async16(ga + (size_t)(32 * r) * K, lA + r * 4096);
#pragma unroll
    for (int r = 0; r < 4; r++) async16(gb + (size_t)(32 * r) * K, lB + r * 4096);
    ga += 64;
    gb += 64;
    __syncthreads();   // drains vmcnt: tile staged
#pragma unroll
    for (int kk = 0; kk < 2; kk++) {
      const int cx = kk ? cx1 : cx0;
      bf16x8 afr[4], bfr[4];
#pragma unroll
      for (int m = 0; m < 4; m++) afr[m] = *(const bf16x8*)((char*)As + arow + m * 2048 + cx);
#pragma unroll
      for (int n = 0; n < 4; n++) bfr[n] = *(const bf16x8*)((char*)Bs + brow + n * 2048 + cx);
#pragma unroll
      for (int m = 0; m < 4; m++)
#pragma unroll
        for (int n = 0; n < 4; n++) mfma16(acc[m][n], afr[m], bfr[n]);
    }
    __syncthreads();   // protect buffer reuse
  }
  mfma_fence();

  const int crow = row0 + wr + g * 4;
  const int ccol = col0 + wc + lrow;
#pragma unroll
  for (int m = 0; m < 4; m++) {
#pragma unroll
    for (int i = 0; i < 4; i++) {
      int grow = crow + m * 16 + i;
#pragma unroll
      for (int n = 0; n < 4; n++) {
        int gcol = ccol + n * 16;
        float v = acc[m][n][i] + bias[gcol];
        size_t oidx = (size_t)grow * N + gcol;
        if constexpr (EPI == 0) {
          ((ushort_t*)outp)[oidx] = f2bf(v);
        } else if constexpr (EPI == 1) {
          ((ushort_t*)outp)[oidx] = f2bf(v > 0.f ? v : 0.f);
        } else if constexpr (EPI == 2) {
          int bb = grow & 3;
          ((float*)outp)[oidx] = res[oidx] + gmod[bb * MOD6 + gcol] * v;
        } else if constexpr (EPI == 3) {
          int bb = grow & 3;
          ((ushort_t*)outp)[oidx] = f2bf(res[oidx] + gmod[bb * MOD6 + gcol] * v);
        } else {
          int bb = grow & 3;
          ((float*)outp)[oidx] =
              bf2f(((const ushort_t*)res)[oidx]) + gmod[bb * MOD6 + gcol] * v;
        }
      }
    }
  }
}

extern "C" void kernel_launch(void* const* d_in, const int* in_sizes, int n_in,
                              void* d_out, int out_size, void* d_ws, size_t ws_size,
                              hipStream_t stream) {
  const float* x     = (const float*)d_in[0];
  const float* c     = (const float*)d_in[1];
  const float* ada_w = (const float*)d_in[2];
  const float* ada_b = (const float*)d_in[3];
  const float* in_w  = (const float*)d_in[4];
  const float* in_b  = (const float*)d_in[5];
  const float* out_w = (const float*)d_in[6];
  const float* out_b = (const float*)d_in[7];
  const float* w1    = (const float*)d_in[8];
  const float* b1    = (const float*)d_in[9];
  const float* w2    = (const float*)d_in[10];
  const float* b2    = (const float*)d_in[11];

  char* ws = (char*)d_ws;
  float* mod    = (float*)ws;                       //      98,304 B  [B,6D] fp32
  ushort_t* wq  = (ushort_t*)(ws + 98304);          //   6,291,456 B  in_proj bf16
  ushort_t* wo  = (ushort_t*)(ws + 6389760);        //   2,097,152 B  out_proj bf16
  ushort_t* wm1 = (ushort_t*)(ws + 8486912);        //   8,388,608 B  mlp_w1 bf16
  ushort_t* wm2 = (ushort_t*)(ws + 16875520);       //   8,388,608 B  mlp_w2 bf16
  ushort_t* xm  = (ushort_t*)(ws + 25264128);       //  16,777,216 B  LN out bf16
  ushort_t* qkv = (ushort_t*)(ws + 42041344);       //  50,331,648 B  qkv bf16
  ushort_t* att = (ushort_t*)(ws + 92372992);       //  16,777,216 B  attn out bf16
  ushort_t* h   = (ushort_t*)(ws + 42041344);       //  67,108,864 B  (reuses qkv+att)
  // optional bf16 x1 (gated on workspace size; falls back to f32 x1 in d_out)
  const size_t X1B_OFF = 109150208;                 //  16,777,216 B  x1 bf16
  const bool big_ws = ws_size >= X1B_OFF + 16777216;
  ushort_t* x1b = (ushort_t*)(ws + X1B_OFF);
  float* x1f = (float*)d_out;

  // all four weight casts in one launch
  castk_all<<<(N4_ALL + 255) / 256, 256, 0, stream>>>(
      (const float4*)in_w, (const float4*)out_w, (const float4*)w1, (const float4*)w2,
      (ushort4*)wq, (ushort4*)wo, (ushort4*)wm1, (ushort4*)wm2);

  ada_k<<<MOD6, 256, 0, stream>>>(c, ada_w, ada_b, mod);

  // xm = LN(x)*(1+sc_msa)+sh_msa
  ln_mod<0><<<MROWS, 256, 0, stream>>>(x, mod, 0, 1024, xm);
  // qkv = xm @ in_proj_w^T + in_proj_b
  gemm_bt<0, 1024><<<dim3(3072 / 128, MROWS / 128), 256, 0, stream>>>(xm, wq, in_b, nullptr, nullptr, qkv, MROWS, 3072);
  // windowed attention (MFMA banded, one wave per (b,h,32-query block))
  attn_mfma<<<(BATCH * NHEAD * (S_LEN / 32)) / 4, 256, 0, stream>>>(qkv, att);

  if (big_ws) {
    // x1(bf16) = x + g_msa * (att @ out_proj_w^T + out_proj_b)
    gemm_bt<3, 1024><<<dim3(1024 / 128, MROWS / 128), 256, 0, stream>>>(att, wo, out_b, x, mod + 2 * DMODEL, x1b, MROWS, 1024);
    // xm = LN(x1)*(1+sc_mlp)+sh_mlp   (bf16 input)
    ln_mod<1><<<MROWS, 256, 0, stream>>>(x1b, mod, 3 * DMODEL, 4 * DMODEL, xm);
    // h = relu(xm @ mlp_w1^T + mlp_b1)
    gemm_bt<1, 1024><<<dim3(4096 / 128, MROWS / 128), 256, 0, stream>>>(xm, wm1, b1, nullptr, nullptr, h, MROWS, 4096);
    // out(f32) = x1(bf16) + g_mlp * (h @ mlp_w2^T + mlp_b2)
    gemm_bt<4, 4096><<<dim3(1024 / 128, MROWS / 128), 256, 0, stream>>>(h, wm2, b2, (const float*)x1b, mod + 5 * DMODEL, (float*)d_out, MROWS, 1024);
  } else {
    // fallback: f32 x1 lives in d_out (R16-identical path)
    gemm_bt<2, 1024><<<dim3(1024 / 128, MROWS / 128), 256, 0, stream>>>(att, wo, out_b, x, mod + 2 * DMODEL, x1f, MROWS, 1024);
    ln_mod<0><<<MROWS, 256, 0, stream>>>(x1f, mod, 3 * DMODEL, 4 * DMODEL, xm);
    gemm_bt<1, 1024><<<dim3(4096 / 128, MROWS / 128), 256, 0, stream>>>(xm, wm1, b1, nullptr, nullptr, h, MROWS, 4096);
    gemm_bt<2, 4096><<<dim3(1024 / 128, MROWS / 128), 256, 0, stream>>>(h, wm2, b2, x1f, mod + 5 * DMODEL, (float*)d_out, MROWS, 1024);
  }
}

// Round 18
// 312.793 us; speedup vs baseline: 1.1172x; 1.0068x over previous
//
#include <hip/hip_runtime.h>

#define S_LEN 2048
#define BATCH 4
#define DMODEL 1024
#define NHEAD 16
#define MROWS (S_LEN * BATCH)   // 8192
#define MOD6 (6 * DMODEL)       // 6144

typedef float f32x4 __attribute__((ext_vector_type(4)));
typedef short bf16x8 __attribute__((ext_vector_type(8)));
typedef unsigned short ushort_t;

__device__ __forceinline__ unsigned short f2bf(float f) {
  unsigned u = __float_as_uint(f);
  u += 0x7FFF + ((u >> 16) & 1);   // round-to-nearest-even
  return (unsigned short)(u >> 16);
}
__device__ __forceinline__ float bf2f(unsigned short h) {
  return __uint_as_float(((unsigned)h) << 16);
}
__device__ __forceinline__ float wave_sum(float v) {
#pragma unroll
  for (int off = 32; off > 0; off >>= 1) v += __shfl_xor(v, off, 64);
  return v;
}
__device__ __forceinline__ void mfma16(f32x4& c, bf16x8 a, bf16x8 b) {
  asm volatile("v_mfma_f32_16x16x32_bf16 %0, %1, %2, %0" : "+v"(c) : "v"(a), "v"(b));
}
// Fence between MFMA writes and VALU reads of acc: sched_barrier pins all code
// motion; 24 wait-states cover the MFMA->VALU RAW hazard window.
__device__ __forceinline__ void mfma_fence() {
  __builtin_amdgcn_sched_barrier(0);
  asm volatile("s_nop 7\n\ts_nop 7\n\ts_nop 7");
  __builtin_amdgcn_sched_barrier(0);
}
__device__ __forceinline__ void async16(const void* g, void* l) {
  __builtin_amdgcn_global_load_lds((const __attribute__((address_space(1))) void*)g,
                                   (__attribute__((address_space(3))) void*)l, 16, 0, 0);
}

// ------- fused preamble: weight casts (4x fp32->bf16) + ada modulation --------
// Blocks [0, N4_ALL/256): cast; blocks [N4_ALL/256, +6144): mod = relu(c)@ada_w.T+ada_b.
// Both paths byte-identical to the proven standalone kernels; merging removes a
// launch boundary and overlaps ada's latency under the cast's BW stream.
#define N4_INW  786432          // 3072*1024/4
#define N4_OUTW 262144          // 1024*1024/4
#define N4_W1   1048576         // 4096*1024/4
#define N4_W2   1048576         // 1024*4096/4
#define N4_ALL  (N4_INW + N4_OUTW + N4_W1 + N4_W2)
#define NCAST_BLK (N4_ALL / 256)   // 12288
__launch_bounds__(256)
__global__ void prep_k(const float4* __restrict__ inw, const float4* __restrict__ outw,
                       const float4* __restrict__ w1, const float4* __restrict__ w2,
                       ushort4* __restrict__ dq, ushort4* __restrict__ dow,
                       ushort4* __restrict__ dw1, ushort4* __restrict__ dw2,
                       const float* __restrict__ c, const float* __restrict__ aw,
                       const float* __restrict__ ab, float* __restrict__ mod) {
  if (blockIdx.x < NCAST_BLK) {
    int i = blockIdx.x * 256 + threadIdx.x;
    const float4* src;
    ushort4* dst;
    int j = i;
    if (j < N4_INW) { src = inw; dst = dq; }
    else if ((j -= N4_INW) < N4_OUTW) { src = outw; dst = dow; }
    else if ((j -= N4_OUTW) < N4_W1) { src = w1; dst = dw1; }
    else { j -= N4_W1; src = w2; dst = dw2; }
    float4 v = src[j];
    ushort4 o;
    o.x = f2bf(v.x); o.y = f2bf(v.y); o.z = f2bf(v.z); o.w = f2bf(v.w);
    dst[j] = o;
  } else {
    int j = blockIdx.x - NCAST_BLK;   // 0..6143
    int b = threadIdx.x >> 6;         // wave -> batch
    int l = threadIdx.x & 63;
    const float* wrow = aw + (size_t)j * DMODEL;
    const float* crow = c + b * DMODEL;
    float s = 0.f;
#pragma unroll 4
    for (int i = l; i < DMODEL; i += 64) {
      float cv = crow[i];
      cv = cv > 0.f ? cv : 0.f;
      s += cv * wrow[i];
    }
    s = wave_sum(s);
    if (l == 0) mod[b * MOD6 + j] = s + ab[j];
  }
}

// ---------------- LN + AdaLN modulate -> bf16 (f32 or bf16 input) ----------------
template <int BF16IN>
__launch_bounds__(256)
__global__ void ln_mod(const void* __restrict__ xin, const float* __restrict__ mod,
                       int sh_off, int sc_off, ushort_t* __restrict__ out) {
  __shared__ float red[8];
  int row = blockIdx.x;         // s*B + b
  int b = row & 3;
  int tid = threadIdx.x;
  float vv[4];
  if constexpr (BF16IN) {
    ushort4 v4 = ((const ushort4*)((const ushort_t*)xin + (size_t)row * DMODEL))[tid];
    vv[0] = bf2f(v4.x); vv[1] = bf2f(v4.y); vv[2] = bf2f(v4.z); vv[3] = bf2f(v4.w);
  } else {
    float4 v = ((const float4*)((const float*)xin + (size_t)row * DMODEL))[tid];
    vv[0] = v.x; vv[1] = v.y; vv[2] = v.z; vv[3] = v.w;
  }
  float s = vv[0] + vv[1] + vv[2] + vv[3];
  float s2 = vv[0] * vv[0] + vv[1] * vv[1] + vv[2] * vv[2] + vv[3] * vv[3];
  s = wave_sum(s);
  s2 = wave_sum(s2);
  int w = tid >> 6, l = tid & 63;
  if (l == 0) { red[w] = s; red[4 + w] = s2; }
  __syncthreads();
  s = red[0] + red[1] + red[2] + red[3];
  s2 = red[4] + red[5] + red[6] + red[7];
  float mean = s * (1.0f / DMODEL);
  float var = s2 * (1.0f / DMODEL) - mean * mean;
  float inv = rsqrtf(var + 1e-6f);
  const float* shp = mod + b * MOD6 + sh_off;
  const float* scp = mod + b * MOD6 + sc_off;
  ushort4 ov;
  ushort_t* op = (ushort_t*)&ov;
#pragma unroll
  for (int j = 0; j < 4; j++) {
    int idx = tid * 4 + j;
    float y = (vv[j] - mean) * inv * (1.0f + scp[idx]) + shp[idx];
    op[j] = f2bf(y);
  }
  ((ushort4*)(out + (size_t)row * DMODEL))[tid] = ov;
}

// ---------------- banded attention via MFMA: one wave per (b,h,qblock of 32) -----
__launch_bounds__(256)
__global__ void attn_mfma(const ushort_t* __restrict__ qkv, ushort_t* __restrict__ out) {
  const int l = threadIdx.x & 63;
  const int widx = blockIdx.x * 4 + (threadIdx.x >> 6);   // 0..4095
  const int qblk = widx & 63;
  const int bh = widx >> 6;
  const int h = bh & 15;
  const int b = bh >> 4;
  const int q0 = qblk * 32;
  int k0 = q0 - 16;
  if (k0 < 0) k0 = 0;
  if (k0 > S_LEN - 64) k0 = S_LEN - 64;
  const int lr = l & 15;
  const int g = l >> 4;

  const char* base = (const char*)qkv;   // row (s*4+b) stride 6144 B; K at +2048B, V at +4096B

  bf16x8 qf[2][2], kf[4][2];
#pragma unroll
  for (int nt = 0; nt < 2; nt++) {
    size_t rowb = (size_t)((q0 + 16 * nt + lr) * 4 + b) * 6144 + h * 128 + 16 * g;
#pragma unroll
    for (int ks = 0; ks < 2; ks++)
      qf[nt][ks] = *(const bf16x8*)(base + rowb + 64 * ks);
  }
#pragma unroll
  for (int mt = 0; mt < 4; mt++) {
    size_t rowb = (size_t)((k0 + 16 * mt + lr) * 4 + b) * 6144 + 2048 + h * 128 + 16 * g;
#pragma unroll
    for (int ks = 0; ks < 2; ks++)
      kf[mt][ks] = *(const bf16x8*)(base + rowb + 64 * ks);
  }

  f32x4 acc[4][2] = {};
  __builtin_amdgcn_s_setprio(1);
#pragma unroll
  for (int mt = 0; mt < 4; mt++)
#pragma unroll
    for (int nt = 0; nt < 2; nt++)
#pragma unroll
      for (int ks = 0; ks < 2; ks++)
        mfma16(acc[mt][nt], kf[mt][ks], qf[nt][ks]);
  __builtin_amdgcn_s_setprio(0);
  mfma_fence();

  float p0[16], p1[16];
  const int sq0 = q0 + lr, sq1 = q0 + 16 + lr;
  float m0 = -1e30f, m1 = -1e30f;
#pragma unroll
  for (int mt = 0; mt < 4; mt++)
#pragma unroll
    for (int i = 0; i < 4; i++) {
      int sk = k0 + 16 * mt + 4 * g + i;
      int d0 = sq0 - sk, d1 = sq1 - sk;
      float s0 = (d0 <= 16 && d0 >= -16) ? acc[mt][0][i] * 0.125f : -1e30f;
      float s1 = (d1 <= 16 && d1 >= -16) ? acc[mt][1][i] * 0.125f : -1e30f;
      p0[mt * 4 + i] = s0;
      p1[mt * 4 + i] = s1;
      m0 = fmaxf(m0, s0);
      m1 = fmaxf(m1, s1);
    }
  m0 = fmaxf(m0, __shfl_xor(m0, 16, 64));
  m0 = fmaxf(m0, __shfl_xor(m0, 32, 64));
  m1 = fmaxf(m1, __shfl_xor(m1, 16, 64));
  m1 = fmaxf(m1, __shfl_xor(m1, 32, 64));
  float l0 = 0.f, l1 = 0.f;
#pragma unroll
  for (int j = 0; j < 16; j++) {
    float e0 = __expf(p0[j] - m0);
    float e1 = __expf(p1[j] - m1);
    p0[j] = e0; p1[j] = e1;
    l0 += e0; l1 += e1;
  }
  l0 += __shfl_xor(l0, 16, 64); l0 += __shfl_xor(l0, 32, 64);
  l1 += __shfl_xor(l1, 16, 64); l1 += __shfl_xor(l1, 32, 64);
  const float inv0 = 1.0f / l0, inv1 = 1.0f / l1;

  const size_t vb = (size_t)b * 6144 + 4096 + h * 128;
  for (int c = 0; c < 8; c++) {
    float o0[8] = {}, o1[8] = {};
#pragma unroll
    for (int mt = 0; mt < 4; mt++)
#pragma unroll
      for (int i = 0; i < 4; i++) {
        int t = k0 + 16 * mt + 4 * g + i;
        bf16x8 v = *(const bf16x8*)(base + (size_t)t * 24576 + vb + 16 * c);
        float pa = p0[mt * 4 + i], pb = p1[mt * 4 + i];
#pragma unroll
        for (int d = 0; d < 8; d++) {
          float vf = bf2f((unsigned short)v[d]);
          o0[d] += pa * vf;
          o1[d] += pb * vf;
        }
      }
#pragma unroll
    for (int d = 0; d < 8; d++) {
      o0[d] += __shfl_xor(o0[d], 16, 64); o0[d] += __shfl_xor(o0[d], 32, 64);
      o1[d] += __shfl_xor(o1[d], 16, 64); o1[d] += __shfl_xor(o1[d], 32, 64);
    }
    if (g < 2) {   // lanes 0..31 write: q = lr + 16*g, chunk c
      int sq = q0 + 16 * g + lr;
      bf16x8 ov;
#pragma unroll
      for (int d = 0; d < 8; d++) {
        float val = (g ? o1[d] : o0[d]) * (g ? inv1 : inv0);
        ov[d] = (short)f2bf(val);
      }
      *(bf16x8*)((char*)out + (size_t)(sq * 4 + b) * 2048 + h * 128 + c * 16) = ov;
    }
  }
}

// ---------------- bf16 MFMA GEMM: C[M,N] = A[M,K] @ W[N,K]^T (+epilogue) ----------
// R13/R16-verified kernel (MLP-class 79 us, MfmaUtil ~35%, 0 bank conflicts,
// occupancy ~35%, no spills).
// EPI 0: out bf16 = acc + bias
// EPI 1: out bf16 = relu(acc + bias)
// EPI 2: out f32  = res_f32  + gmod[b,col] * (acc + bias)
// EPI 3: out bf16 = res_f32  + gmod[b,col] * (acc + bias)
// EPI 4: out f32  = res_bf16 + gmod[b,col] * (acc + bias)
template <int EPI, int K>
__launch_bounds__(256, 4)
__global__ void gemm_bt(const ushort_t* __restrict__ A, const ushort_t* __restrict__ W,
                        const float* __restrict__ bias, const float* __restrict__ res,
                        const float* __restrict__ gmod, void* __restrict__ outp,
                        int M, int N) {
  __shared__ alignas(16) ushort_t As[128 * 64];  // 16 KB
  __shared__ alignas(16) ushort_t Bs[128 * 64];  // 16 KB
  const int tid = threadIdx.x;
  const int w = tid >> 6;
  const int l = tid & 63;

  // XCD-aware bijective remap: dispatch-linear -> contiguous chunk per XCD.
  int bx = blockIdx.x, by = blockIdx.y;
  {
    const int nbx = gridDim.x;
    const int nwg = nbx * gridDim.y;
    if ((nwg & 7) == 0) {
      int lin = by * nbx + bx;
      int nlin = (lin & 7) * (nwg >> 3) + (lin >> 3);
      bx = nlin % nbx;
      by = nlin / nbx;
    }
  }
  const int row0 = by * 128;
  const int col0 = bx * 128;
  const int wr = (w >> 1) * 64;
  const int wc = (w & 1) * 64;

  f32x4 acc[4][4] = {};

  // staging: thread tid -> slot (row = tid>>3 + 32r, chunk = tid&7);
  // source global chunk = (tid&7) ^ ((tid>>3)&7)   [row&7 == (tid>>3)&7]
  const int srow = tid >> 3;
  const int scc = (((tid & 7) ^ (srow & 7)) << 3);   // bf16 column
  const ushort_t* ga = A + (size_t)(row0 + srow) * K + scc;
  const ushort_t* gb = W + (size_t)(col0 + srow) * K + scc;
  char* lA = (char*)As + w * 1024;   // wave-uniform; HW adds lane*16; +4096/round
  char* lB = (char*)Bs + w * 1024;

  // read offsets: frag (tile, kk) at row wr|wc + tile*16 + lrow, global chunk kk*4+g
  const int lrow = l & 15;
  const int g = l >> 4;
  const int cx0 = ((g ^ (lrow & 7)) << 4);         // kk=0
  const int cx1 = (((4 + g) ^ (lrow & 7)) << 4);   // kk=1
  const int arow = (wr + lrow) * 128;
  const int brow = (wc + lrow) * 128;

  const int nk = K >> 6;
  for (int it = 0; it < nk; ++it) {
#pragma unroll
    for (int r = 0; r < 4; r++) async16(ga + (size_t)(32 * r) * K, lA + r * 4096);
#pragma unroll
    for (int r = 0; r < 4; r++) async16(gb + (size_t)(32 * r) * K, lB + r * 4096);
    ga += 64;
    gb += 64;
    __syncthreads();   // drains vmcnt: tile staged
#pragma unroll
    for (int kk = 0; kk < 2; kk++) {
      const int cx = kk ? cx1 : cx0;
      bf16x8 afr[4], bfr[4];
#pragma unroll
      for (int m = 0; m < 4; m++) afr[m] = *(const bf16x8*)((char*)As + arow + m * 2048 + cx);
#pragma unroll
      for (int n = 0; n < 4; n++) bfr[n] = *(const bf16x8*)((char*)Bs + brow + n * 2048 + cx);
#pragma unroll
      for (int m = 0; m < 4; m++)
#pragma unroll
        for (int n = 0; n < 4; n++) mfma16(acc[m][n], afr[m], bfr[n]);
    }
    __syncthreads();   // protect buffer reuse
  }
  mfma_fence();

  const int crow = row0 + wr + g * 4;
  const int ccol = col0 + wc + lrow;
#pragma unroll
  for (int m = 0; m < 4; m++) {
#pragma unroll
    for (int i = 0; i < 4; i++) {
      int grow = crow + m * 16 + i;
#pragma unroll
      for (int n = 0; n < 4; n++) {
        int gcol = ccol + n * 16;
        float v = acc[m][n][i] + bias[gcol];
        size_t oidx = (size_t)grow * N + gcol;
        if constexpr (EPI == 0) {
          ((ushort_t*)outp)[oidx] = f2bf(v);
        } else if constexpr (EPI == 1) {
          ((ushort_t*)outp)[oidx] = f2bf(v > 0.f ? v : 0.f);
        } else if constexpr (EPI == 2) {
          int bb = grow & 3;
          ((float*)outp)[oidx] = res[oidx] + gmod[bb * MOD6 + gcol] * v;
        } else if constexpr (EPI == 3) {
          int bb = grow & 3;
          ((ushort_t*)outp)[oidx] = f2bf(res[oidx] + gmod[bb * MOD6 + gcol] * v);
        } else {
          int bb = grow & 3;
          ((float*)outp)[oidx] =
              bf2f(((const ushort_t*)res)[oidx]) + gmod[bb * MOD6 + gcol] * v;
        }
      }
    }
  }
}

extern "C" void kernel_launch(void* const* d_in, const int* in_sizes, int n_in,
                              void* d_out, int out_size, void* d_ws, size_t ws_size,
                              hipStream_t stream) {
  const float* x     = (const float*)d_in[0];
  const float* c     = (const float*)d_in[1];
  const float* ada_w = (const float*)d_in[2];
  const float* ada_b = (const float*)d_in[3];
  const float* in_w  = (const float*)d_in[4];
  const float* in_b  = (const float*)d_in[5];
  const float* out_w = (const float*)d_in[6];
  const float* out_b = (const float*)d_in[7];
  const float* w1    = (const float*)d_in[8];
  const float* b1    = (const float*)d_in[9];
  const float* w2    = (const float*)d_in[10];
  const float* b2    = (const float*)d_in[11];

  char* ws = (char*)d_ws;
  float* mod    = (float*)ws;                       //      98,304 B  [B,6D] fp32
  ushort_t* wq  = (ushort_t*)(ws + 98304);          //   6,291,456 B  in_proj bf16
  ushort_t* wo  = (ushort_t*)(ws + 6389760);        //   2,097,152 B  out_proj bf16
  ushort_t* wm1 = (ushort_t*)(ws + 8486912);        //   8,388,608 B  mlp_w1 bf16
  ushort_t* wm2 = (ushort_t*)(ws + 16875520);       //   8,388,608 B  mlp_w2 bf16
  ushort_t* xm  = (ushort_t*)(ws + 25264128);       //  16,777,216 B  LN out bf16
  ushort_t* qkv = (ushort_t*)(ws + 42041344);       //  50,331,648 B  qkv bf16
  ushort_t* att = (ushort_t*)(ws + 92372992);       //  16,777,216 B  attn out bf16
  ushort_t* h   = (ushort_t*)(ws + 42041344);       //  67,108,864 B  (reuses qkv+att)
  // optional bf16 x1 (gated on workspace size; falls back to f32 x1 in d_out)
  const size_t X1B_OFF = 109150208;                 //  16,777,216 B  x1 bf16
  const bool big_ws = ws_size >= X1B_OFF + 16777216;
  ushort_t* x1b = (ushort_t*)(ws + X1B_OFF);
  float* x1f = (float*)d_out;

  // fused preamble: all four weight casts + ada modulation in one launch
  prep_k<<<NCAST_BLK + MOD6, 256, 0, stream>>>(
      (const float4*)in_w, (const float4*)out_w, (const float4*)w1, (const float4*)w2,
      (ushort4*)wq, (ushort4*)wo, (ushort4*)wm1, (ushort4*)wm2,
      c, ada_w, ada_b, mod);

  // xm = LN(x)*(1+sc_msa)+sh_msa
  ln_mod<0><<<MROWS, 256, 0, stream>>>(x, mod, 0, 1024, xm);
  // qkv = xm @ in_proj_w^T + in_proj_b
  gemm_bt<0, 1024><<<dim3(3072 / 128, MROWS / 128), 256, 0, stream>>>(xm, wq, in_b, nullptr, nullptr, qkv, MROWS, 3072);
  // windowed attention (MFMA banded, one wave per (b,h,32-query block))
  attn_mfma<<<(BATCH * NHEAD * (S_LEN / 32)) / 4, 256, 0, stream>>>(qkv, att);

  if (big_ws) {
    // x1(bf16) = x + g_msa * (att @ out_proj_w^T + out_proj_b)
    gemm_bt<3, 1024><<<dim3(1024 / 128, MROWS / 128), 256, 0, stream>>>(att, wo, out_b, x, mod + 2 * DMODEL, x1b, MROWS, 1024);
    // xm = LN(x1)*(1+sc_mlp)+sh_mlp   (bf16 input)
    ln_mod<1><<<MROWS, 256, 0, stream>>>(x1b, mod, 3 * DMODEL, 4 * DMODEL, xm);
    // h = relu(xm @ mlp_w1^T + mlp_b1)
    gemm_bt<1, 1024><<<dim3(4096 / 128, MROWS / 128), 256, 0, stream>>>(xm, wm1, b1, nullptr, nullptr, h, MROWS, 4096);
    // out(f32) = x1(bf16) + g_mlp * (h @ mlp_w2^T + mlp_b2)
    gemm_bt<4, 4096><<<dim3(1024 / 128, MROWS / 128), 256, 0, stream>>>(h, wm2, b2, (const float*)x1b, mod + 5 * DMODEL, (float*)d_out, MROWS, 1024);
  } else {
    // fallback: f32 x1 lives in d_out (R16-identical path)
    gemm_bt<2, 1024><<<dim3(1024 / 128, MROWS / 128), 256, 0, stream>>>(att, wo, out_b, x, mod + 2 * DMODEL, x1f, MROWS, 1024);
    ln_mod<0><<<MROWS, 256, 0, stream>>>(x1f, mod, 3 * DMODEL, 4 * DMODEL, xm);
    gemm_bt<1, 1024><<<dim3(4096 / 128, MROWS / 128), 256, 0, stream>>>(xm, wm1, b1, nullptr, nullptr, h, MROWS, 4096);
    gemm_bt<2, 4096><<<dim3(1024 / 128, MROWS / 128), 256, 0, stream>>>(h, wm2, b2, x1f, mod + 5 * DMODEL, (float*)d_out, MROWS, 1024);
  }
}